// Round 9
// baseline (210.261 us; speedup 1.0000x reference)
//
#include <hip/hip_runtime.h>
#include <stdint.h>

#define TT 512
#define BT 8    // 4096/8 = 512 wgs -> 2 wgs/CU -> 2 waves/SIMD (no dup work)
#define XSTR 516  // x row stride (floats): spreads t-columns across banks

typedef float    f32x4 __attribute__((ext_vector_type(4)));
typedef float    f32x2 __attribute__((ext_vector_type(2)));
typedef short    s16x8 __attribute__((ext_vector_type(8)));
typedef __fp16   h16x2 __attribute__((ext_vector_type(2)));
typedef _Float16 f16x8 __attribute__((ext_vector_type(8)));

#define MFMA_F16(A, B, C) \
    __builtin_amdgcn_mfma_f32_16x16x32_f16( \
        __builtin_bit_cast(f16x8, (A)), (B), (C), 0, 0, 0)

#define LOG2E  1.442695040888963f
#define LOG2E2 2.885390081777927f

// R7 skeleton: 4 waves, wave w owns hidden cols [16w,16w+16), fp16 MFMA
// (6/step/wave), BT=8 with batches on D-rows {0,1,4,5,8,9,12,13} so every
// lane's valid accumulators are regs {0,1} (no duplication, no idle lanes).
// R8 polish: x batch-major in LDS, 4 steps of x loaded per 2 ds_read_b128;
// x folded into MFMA C-init (off the post-MFMA critical chain); cvt_pkrtz
// single-inst f16 pack; 4-step unroll (immediate LDS offsets); anti-phase
// s_sleep stagger for the co-resident partner wg (blockIdx bit 8).
__global__ __launch_bounds__(256, 2) void gru_scan_kernel(
    const float* __restrict__ x,     // (4096, 512, 1)
    const float* __restrict__ Wih,   // (192, 1)
    const float* __restrict__ Whh,   // (192, 64)
    const float* __restrict__ bih,   // (192)
    const float* __restrict__ bhh,   // (192)
    const float* __restrict__ Wout,  // (1, 64)
    const float* __restrict__ bout,  // (1)
    float* __restrict__ out)         // (4096, 1)
{
    __shared__ __align__(16) float xs[BT * XSTR];  // x batch-major [b][t], 16.5 KB
    __shared__ __align__(16) short hbuf[2][1024];  // [dbuf][slot*8+j], 4 KB
    __shared__ float outp[4][BT];

    const int tid  = threadIdx.x;
    const int w    = tid >> 6;
    const int L    = tid & 63;
    const int n16  = L & 15;
    const int quad = L >> 4;
    const int q    = w * 16 + n16;   // hidden col owned by this lane
    const int b0   = blockIdx.x * BT;

    // ---- stage x batch-major: xs[b][t] ----
    #pragma unroll
    for (int k = 0; k < 4; ++k) {
        int idx = tid + k * 256;          // 0..1023
        int row = idx >> 7;               // batch row 0..7
        int t4  = idx & 127;              // t/4
        f32x4 v = *(const f32x4*)(x + (size_t)(b0 + row) * TT + t4 * 4);
        *(f32x4*)(xs + row * XSTR + t4 * 4) = v;   // 16B-aligned (516*4%16==0)
    }
    // ---- zero both h double-buffers (4 KB = 256 f32x4) ----
    {
        f32x4* hb = (f32x4*)hbuf;
        f32x4 zv = {0.f, 0.f, 0.f, 0.f};
        hb[tid] = zv;
    }

    // ---- per-lane constants (gate scales folded) ----
    const float wr2   = -LOG2E  * Wih[q];
    const float wz2   = -LOG2E  * Wih[64 + q];
    const float wn2   =  LOG2E2 * Wih[128 + q];
    const float bR2   = -LOG2E  * (bih[q]      + bhh[q]);
    const float bZ2   = -LOG2E  * (bih[64 + q] + bhh[64 + q]);
    const float bN2   =  LOG2E2 * bhh[128 + q];
    const float bihn2 =  LOG2E2 * bih[128 + q];
    const float wo    = Wout[q];

    // ---- W_hh B-fragments (scaled), fp16 RNE ----
    f16x8 Bf[3][2];
    #pragma unroll
    for (int g = 0; g < 3; ++g) {
        const float sg = (g == 2) ? LOG2E2 : -LOG2E;
        #pragma unroll
        for (int c = 0; c < 2; ++c) {
            const float* p = Whh + ((g * 64 + q) * 64 + c * 32 + quad * 8);
            #pragma unroll
            for (int j = 0; j < 8; ++j)
                Bf[g][c][j] = (_Float16)(p[j] * sg);
        }
    }

    // persistent h (fp32): lane handles batches b = quad*2 + {0,1}
    float hD[2] = {0.f, 0.f};

    // ---- swizzled LDS addressing (R6 scheme) ----
    const int kg   = q >> 3;
    const int sxor = (kg & 1) * 4;
    int waddr[2];
    #pragma unroll
    for (int p = 0; p < 2; ++p)
        waddr[p] = (kg * 16 + ((p * 4 + quad) ^ sxor)) * 8 + (q & 7);

    const int permx = ((n16 & 3) * 4 + (n16 >> 2)) ^ ((quad & 1) * 4);
    const int rslot = quad * 16 + permx;

    const s16x8* hbv = (const s16x8*)hbuf;   // 256 slots of 8 shorts
    const float* xrow0 = xs + (quad * 2) * XSTR;
    const float* xrow1 = xrow0 + XSTR;

    // ---- anti-phase stagger: delay the presumed co-resident partner wg ----
    if ((blockIdx.x >> 8) & 1) __builtin_amdgcn_s_sleep(6);  // ~384 cyc

    auto step = [&](int cur, f32x2 xv) {
        // C-init with x folded in (pre-MFMA, off the critical chain);
        // regs 2,3 are junk-but-finite (their A-rows are zero, D never read)
        f32x2 cr2 = xv * wr2 + bR2;
        f32x2 cz2 = xv * wz2 + bZ2;
        f32x4 cR = {cr2[0], cr2[1], cr2[0], cr2[1]};
        f32x4 cZ = {cz2[0], cz2[1], cz2[0], cz2[1]};
        f32x4 cN = {bN2, bN2, bN2, bN2};

        __syncthreads();

        s16x8 A0 = hbv[cur * 128 +  0 + rslot];
        s16x8 A1 = hbv[cur * 128 + 64 + rslot];

        // r-gate first (heads the serial chain), z last
        f32x4 aR = MFMA_F16(A0, Bf[0][0], cR);
        aR       = MFMA_F16(A1, Bf[0][1], aR);
        f32x4 aN = MFMA_F16(A0, Bf[2][0], cN);
        aN       = MFMA_F16(A1, Bf[2][1], aN);
        f32x4 aZ = MFMA_F16(A0, Bf[1][0], cZ);
        aZ       = MFMA_F16(A1, Bf[1][1], aZ);

        short* wh = (short*)hbuf + (cur ^ 1) * 1024;

        f32x2 aRp = {aR[0], aR[1]};
        f32x2 aZp = {aZ[0], aZ[1]};
        f32x2 aNp = {aN[0], aN[1]};
        f32x2 hp  = {hD[0], hD[1]};

        f32x2 Er = {__builtin_amdgcn_exp2f(aRp[0]), __builtin_amdgcn_exp2f(aRp[1])};
        f32x2 DR = Er + 1.0f;
        f32x2 r  = {__builtin_amdgcn_rcpf(DR[0]), __builtin_amdgcn_rcpf(DR[1])};
        f32x2 Ez = {__builtin_amdgcn_exp2f(aZp[0]), __builtin_amdgcn_exp2f(aZp[1])};
        f32x2 DZ = Ez + 1.0f;
        f32x2 xn = xv * wn2 + bihn2;
        f32x2 an = r * aNp + xn;
        f32x2 En = {__builtin_amdgcn_exp2f(an[0]), __builtin_amdgcn_exp2f(an[1])};
        f32x2 DN = En + 1.0f;
        f32x2 P  = DZ * DN;
        f32x2 iq = {__builtin_amdgcn_rcpf(P[0]), __builtin_amdgcn_rcpf(P[1])};
        f32x2 z  = iq * DN;                  // = 1/DZ = sigmoid(pre_z)
        f32x2 rn = iq * DZ;                  // = 1/DN
        f32x2 n  = rn * -2.0f + 1.0f;        // tanh
        f32x2 hn = z * (hp - n) + n;         // (1-z)n + z h

        hD[0] = hn[0]; hD[1] = hn[1];

        h16x2 hpk = __builtin_amdgcn_cvt_pkrtz(hn[0], hn[1]);
        unsigned upk = __builtin_bit_cast(unsigned, hpk);
        wh[waddr[0]] = (short)(upk & 0xffffu);
        wh[waddr[1]] = (short)(upk >> 16);
    };

    for (int t = 0; t < TT; t += 4) {
        f32x4 xa = *(const f32x4*)(xrow0 + t);   // batch b0, steps t..t+3
        f32x4 xb = *(const f32x4*)(xrow1 + t);   // batch b1, steps t..t+3
        step(0, f32x2{xa[0], xb[0]});
        step(1, f32x2{xa[1], xb[1]});
        step(0, f32x2{xa[2], xb[2]});
        step(1, f32x2{xa[3], xb[3]});
    }

    // ---- epilogue: out[b] = sum_q h[b][q]*Wout[q] + bout ----
    float p0 = hD[0] * wo;
    float p1 = hD[1] * wo;
    #pragma unroll
    for (int mask = 1; mask <= 8; mask <<= 1) {
        p0 += __shfl_xor(p0, mask, 64);
        p1 += __shfl_xor(p1, mask, 64);
    }
    if (n16 == 0) {
        outp[w][quad * 2]     = p0;
        outp[w][quad * 2 + 1] = p1;
    }
    __syncthreads();
    if (tid < BT) {
        out[b0 + tid] = outp[0][tid] + outp[1][tid] + outp[2][tid] + outp[3][tid] + bout[0];
    }
}

extern "C" void kernel_launch(void* const* d_in, const int* in_sizes, int n_in,
                              void* d_out, int out_size, void* d_ws, size_t ws_size,
                              hipStream_t stream) {
    (void)in_sizes; (void)n_in; (void)d_ws; (void)ws_size; (void)out_size;
    const float* x    = (const float*)d_in[0];
    const float* Wih  = (const float*)d_in[1];
    const float* Whh  = (const float*)d_in[2];
    const float* bih  = (const float*)d_in[3];
    const float* bhh  = (const float*)d_in[4];
    const float* Wout = (const float*)d_in[5];
    const float* bout = (const float*)d_in[6];
    float* out = (float*)d_out;

    gru_scan_kernel<<<dim3(4096 / BT), dim3(256), 0, stream>>>(
        x, Wih, Whh, bih, bhh, Wout, bout, out);
}

// Round 10
// 195.888 us; speedup vs baseline: 1.0734x; 1.0734x over previous
//
#include <hip/hip_runtime.h>
#include <stdint.h>

#define TT 512
#define BT 8    // 4096/8 = 512 wgs -> 2 wgs/CU -> 2 waves/SIMD (no dup work)
#define XSTR 516  // x row stride (floats): spreads t-columns across banks

typedef float    f32x4 __attribute__((ext_vector_type(4)));
typedef float    f32x2 __attribute__((ext_vector_type(2)));
typedef short    s16x8 __attribute__((ext_vector_type(8)));
typedef __fp16   h16x2 __attribute__((ext_vector_type(2)));
typedef _Float16 f16x8 __attribute__((ext_vector_type(8)));

#define MFMA_F16(A, B, C) \
    __builtin_amdgcn_mfma_f32_16x16x32_f16( \
        __builtin_bit_cast(f16x8, (A)), (B), (C), 0, 0, 0)

#define LOG2E  1.442695040888963f
#define LOG2E2 2.885390081777927f

// R7 skeleton: 4 waves, wave w owns hidden cols [16w,16w+16), fp16 MFMA
// (6/step/wave), BT=8 with batches on D-rows {0,1,4,5,8,9,12,13} so every
// lane's valid accumulators are regs {0,1}: no duplication, no idle lanes.
// Memory layout (R9, proven zero-conflict): x batch-major in LDS (b128 per
// 4 steps), swizzled h exchange, cvt_pkrtz pack, 4-step unroll.
// C-operand = loop-invariant bias vectors (MFMA reads C / writes D: zero
// per-step cost — R9's per-step C build cost ~12 movs, reverted).
__global__ __launch_bounds__(256, 2) void gru_scan_kernel(
    const float* __restrict__ x,     // (4096, 512, 1)
    const float* __restrict__ Wih,   // (192, 1)
    const float* __restrict__ Whh,   // (192, 64)
    const float* __restrict__ bih,   // (192)
    const float* __restrict__ bhh,   // (192)
    const float* __restrict__ Wout,  // (1, 64)
    const float* __restrict__ bout,  // (1)
    float* __restrict__ out)         // (4096, 1)
{
    __shared__ __align__(16) float xs[BT * XSTR];  // x batch-major [b][t], 16.5 KB
    __shared__ __align__(16) short hbuf[2][1024];  // [dbuf][slot*8+j], 4 KB
    __shared__ float outp[4][BT];

    const int tid  = threadIdx.x;
    const int w    = tid >> 6;
    const int L    = tid & 63;
    const int n16  = L & 15;
    const int quad = L >> 4;
    const int q    = w * 16 + n16;   // hidden col owned by this lane
    const int b0   = blockIdx.x * BT;

    // ---- stage x batch-major: xs[b][t] ----
    #pragma unroll
    for (int k = 0; k < 4; ++k) {
        int idx = tid + k * 256;          // 0..1023
        int row = idx >> 7;               // batch row 0..7
        int t4  = idx & 127;              // t/4
        f32x4 v = *(const f32x4*)(x + (size_t)(b0 + row) * TT + t4 * 4);
        *(f32x4*)(xs + row * XSTR + t4 * 4) = v;   // 16B-aligned (516*4%16==0)
    }
    // ---- zero both h double-buffers (4 KB = 256 f32x4) ----
    {
        f32x4* hb = (f32x4*)hbuf;
        f32x4 zv = {0.f, 0.f, 0.f, 0.f};
        hb[tid] = zv;
    }

    // ---- per-lane constants (gate scales folded) ----
    const float wr2   = -LOG2E  * Wih[q];
    const float wz2   = -LOG2E  * Wih[64 + q];
    const float wn2   =  LOG2E2 * Wih[128 + q];
    const float bR2   = -LOG2E  * (bih[q]      + bhh[q]);
    const float bZ2   = -LOG2E  * (bih[64 + q] + bhh[64 + q]);
    const float bN2   =  LOG2E2 * bhh[128 + q];
    const float bihn2 =  LOG2E2 * bih[128 + q];
    const float wo    = Wout[q];

    const f32x4 bR4 = {bR2, bR2, bR2, bR2};
    const f32x4 bZ4 = {bZ2, bZ2, bZ2, bZ2};
    const f32x4 bN4 = {bN2, bN2, bN2, bN2};

    // ---- W_hh B-fragments (scaled), fp16 RNE ----
    f16x8 Bf[3][2];
    #pragma unroll
    for (int g = 0; g < 3; ++g) {
        const float sg = (g == 2) ? LOG2E2 : -LOG2E;
        #pragma unroll
        for (int c = 0; c < 2; ++c) {
            const float* p = Whh + ((g * 64 + q) * 64 + c * 32 + quad * 8);
            #pragma unroll
            for (int j = 0; j < 8; ++j)
                Bf[g][c][j] = (_Float16)(p[j] * sg);
        }
    }

    // persistent h (fp32): lane handles batches b = quad*2 + {0,1}
    float hD[2] = {0.f, 0.f};

    // ---- swizzled LDS addressing (zero-conflict, proven R9) ----
    const int kg   = q >> 3;
    const int sxor = (kg & 1) * 4;
    int waddr[2];
    #pragma unroll
    for (int p = 0; p < 2; ++p)
        waddr[p] = (kg * 16 + ((p * 4 + quad) ^ sxor)) * 8 + (q & 7);

    const int permx = ((n16 & 3) * 4 + (n16 >> 2)) ^ ((quad & 1) * 4);
    const int rslot = quad * 16 + permx;

    const s16x8* hbv = (const s16x8*)hbuf;   // 256 slots of 8 shorts
    const float* xrow0 = xs + (quad * 2) * XSTR;
    const float* xrow1 = xrow0 + XSTR;

    // ---- anti-phase stagger for the co-resident partner wg (b, b+256) ----
    if ((blockIdx.x >> 8) & 1) __builtin_amdgcn_s_sleep(6);  // ~384 cyc, once

    auto step = [&](int cur, f32x2 xv) {
        __syncthreads();

        s16x8 A0 = hbv[cur * 128 +  0 + rslot];
        s16x8 A1 = hbv[cur * 128 + 64 + rslot];

        // r-gate first (heads the serial chain), z last
        f32x4 aR = MFMA_F16(A0, Bf[0][0], bR4);
        aR       = MFMA_F16(A1, Bf[0][1], aR);
        f32x4 aN = MFMA_F16(A0, Bf[2][0], bN4);
        aN       = MFMA_F16(A1, Bf[2][1], aN);
        f32x4 aZ = MFMA_F16(A0, Bf[1][0], bZ4);
        aZ       = MFMA_F16(A1, Bf[1][1], aZ);

        short* wh = (short*)hbuf + (cur ^ 1) * 1024;

        f32x2 aRp = {aR[0], aR[1]};
        f32x2 aZp = {aZ[0], aZ[1]};
        f32x2 aNp = {aN[0], aN[1]};
        f32x2 hp  = {hD[0], hD[1]};

        f32x2 ar = xv * wr2 + aRp;
        f32x2 Er = {__builtin_amdgcn_exp2f(ar[0]), __builtin_amdgcn_exp2f(ar[1])};
        f32x2 DR = Er + 1.0f;
        f32x2 r  = {__builtin_amdgcn_rcpf(DR[0]), __builtin_amdgcn_rcpf(DR[1])};
        f32x2 az = xv * wz2 + aZp;
        f32x2 Ez = {__builtin_amdgcn_exp2f(az[0]), __builtin_amdgcn_exp2f(az[1])};
        f32x2 DZ = Ez + 1.0f;
        f32x2 xn = xv * wn2 + bihn2;
        f32x2 an = r * aNp + xn;
        f32x2 En = {__builtin_amdgcn_exp2f(an[0]), __builtin_amdgcn_exp2f(an[1])};
        f32x2 DN = En + 1.0f;
        f32x2 P  = DZ * DN;
        f32x2 iq = {__builtin_amdgcn_rcpf(P[0]), __builtin_amdgcn_rcpf(P[1])};
        f32x2 z  = iq * DN;                  // = 1/DZ = sigmoid(pre_z)
        f32x2 rn = iq * DZ;                  // = 1/DN
        f32x2 n  = rn * -2.0f + 1.0f;        // tanh
        f32x2 hn = z * (hp - n) + n;         // (1-z)n + z h

        hD[0] = hn[0]; hD[1] = hn[1];

        h16x2 hpk = __builtin_amdgcn_cvt_pkrtz(hn[0], hn[1]);
        unsigned upk = __builtin_bit_cast(unsigned, hpk);
        wh[waddr[0]] = (short)(upk & 0xffffu);
        wh[waddr[1]] = (short)(upk >> 16);
    };

    for (int t = 0; t < TT; t += 4) {
        f32x4 xa = *(const f32x4*)(xrow0 + t);   // batch b0, steps t..t+3
        f32x4 xb = *(const f32x4*)(xrow1 + t);   // batch b1, steps t..t+3
        step(0, f32x2{xa[0], xb[0]});
        step(1, f32x2{xa[1], xb[1]});
        step(0, f32x2{xa[2], xb[2]});
        step(1, f32x2{xa[3], xb[3]});
    }

    // ---- epilogue: out[b] = sum_q h[b][q]*Wout[q] + bout ----
    float p0 = hD[0] * wo;
    float p1 = hD[1] * wo;
    #pragma unroll
    for (int mask = 1; mask <= 8; mask <<= 1) {
        p0 += __shfl_xor(p0, mask, 64);
        p1 += __shfl_xor(p1, mask, 64);
    }
    if (n16 == 0) {
        outp[w][quad * 2]     = p0;
        outp[w][quad * 2 + 1] = p1;
    }
    __syncthreads();
    if (tid < BT) {
        out[b0 + tid] = outp[0][tid] + outp[1][tid] + outp[2][tid] + outp[3][tid] + bout[0];
    }
}

extern "C" void kernel_launch(void* const* d_in, const int* in_sizes, int n_in,
                              void* d_out, int out_size, void* d_ws, size_t ws_size,
                              hipStream_t stream) {
    (void)in_sizes; (void)n_in; (void)d_ws; (void)ws_size; (void)out_size;
    const float* x    = (const float*)d_in[0];
    const float* Wih  = (const float*)d_in[1];
    const float* Whh  = (const float*)d_in[2];
    const float* bih  = (const float*)d_in[3];
    const float* bhh  = (const float*)d_in[4];
    const float* Wout = (const float*)d_in[5];
    const float* bout = (const float*)d_in[6];
    float* out = (float*)d_out;

    gru_scan_kernel<<<dim3(4096 / BT), dim3(256), 0, stream>>>(
        x, Wih, Whh, bih, bhh, Wout, bout, out);
}